// Round 8
// baseline (3324.517 us; speedup 1.0000x reference)
//
#include <hip/hip_runtime.h>
#include <hip/hip_bf16.h>

typedef __hip_bfloat16 bf16;
typedef short s16x8 __attribute__((ext_vector_type(8)));
typedef float f32x4 __attribute__((ext_vector_type(4)));

// Problem constants
#define HN 4
#define DM 256
#define KF 1024
#define FFD 1024
#define LL 2048
#define BB 4
#define NN (LL * BB)   // 8192
#define HD (HN * DM)   // 1024

// ---------------- reductions ----------------
__device__ __forceinline__ float waveReduceSum(float v) {
    for (int o = 32; o; o >>= 1) v += __shfl_down(v, o, 64);
    return v;
}
__device__ __forceinline__ float waveReduceMax(float v) {
    for (int o = 32; o; o >>= 1) v = fmaxf(v, __shfl_down(v, o, 64));
    return v;
}
__device__ __forceinline__ float blockReduceSum(float v) {
    __shared__ float sh[4];
    v = waveReduceSum(v);
    __syncthreads();
    if ((threadIdx.x & 63) == 0) sh[threadIdx.x >> 6] = v;
    __syncthreads();
    return sh[0] + sh[1] + sh[2] + sh[3];
}
__device__ __forceinline__ float blockReduceMax(float v) {
    __shared__ float sh[4];
    v = waveReduceMax(v);
    __syncthreads();
    if ((threadIdx.x & 63) == 0) sh[threadIdx.x >> 6] = v;
    __syncthreads();
    return fmaxf(fmaxf(sh[0], sh[1]), fmaxf(sh[2], sh[3]));
}

// ---------------- diagnostic sentinel (writes f32 now) ----------------
__global__ void sentinel_kernel(float* out, float val) {
    if (threadIdx.x == 0 && blockIdx.x == 0) out[0] = val;
}

// ---------------- MFMA GEMM ----------------
// C = accSign*(A @ B^T) [+bias_f32[col]] [+aux] [relu]
// A: (M x Kc) row-major lda, dtype by aF32 (f32 converted to bf16 at staging).
// B: (N x Kc) row-major ldb, dtype by bF32. C: (M x N) ldc, dtype by cF32.
// auxType: 0 none, 1 f32, 2 bf16. Requires M%128==0, N%128==0, Kc%32==0.
#define BKT 32
#define LDST 40  // padded LDS row stride (bf16 elems)

__global__ __launch_bounds__(256) void gemm_nt(
    const void* __restrict__ A, int aF32, int lda,
    const void* __restrict__ Bv, int bF32, int ldb,
    void* __restrict__ C, int cF32, int ldc,
    int Kc,
    const float* __restrict__ bias,
    const void* __restrict__ aux, int auxType, int ldaux,
    float accSign, int relu)
{
    __shared__ bf16 As[128 * LDST];
    __shared__ bf16 Bs[128 * LDST];

    const int tid = threadIdx.x;
    const int lane = tid & 63;
    const int wave = tid >> 6;
    const int wm = wave & 1;
    const int wn = wave >> 1;
    const int lrow = lane & 15;
    const int quad = lane >> 4;

    const int m0 = blockIdx.x * 128;
    const int n0 = blockIdx.y * 128;

    const int srow = tid >> 1;        // 0..127
    const int scol = (tid & 1) * 16;  // 0 or 16

    f32x4 acc[4][4] = {};

    for (int k0 = 0; k0 < Kc; k0 += BKT) {
        uint4 av0, av1, bv0, bv1;
        if (aF32) {
            const float* ag = (const float*)A + (long)(m0 + srow) * lda + k0 + scol;
            ushort t[16];
#pragma unroll
            for (int j = 0; j < 4; j++) {
                float4 f = *(const float4*)(ag + 4 * j);
                bf16 b0 = (bf16)f.x, b1 = (bf16)f.y, b2 = (bf16)f.z, b3 = (bf16)f.w;
                __builtin_memcpy(&t[4 * j + 0], &b0, 2);
                __builtin_memcpy(&t[4 * j + 1], &b1, 2);
                __builtin_memcpy(&t[4 * j + 2], &b2, 2);
                __builtin_memcpy(&t[4 * j + 3], &b3, 2);
            }
            av0 = *(const uint4*)&t[0];
            av1 = *(const uint4*)&t[8];
        } else {
            const bf16* ag = (const bf16*)A + (long)(m0 + srow) * lda + k0 + scol;
            av0 = *(const uint4*)(ag);
            av1 = *(const uint4*)(ag + 8);
        }
        if (bF32) {
            const float* bg = (const float*)Bv + (long)(n0 + srow) * ldb + k0 + scol;
            ushort t[16];
#pragma unroll
            for (int j = 0; j < 4; j++) {
                float4 f = *(const float4*)(bg + 4 * j);
                bf16 b0 = (bf16)f.x, b1 = (bf16)f.y, b2 = (bf16)f.z, b3 = (bf16)f.w;
                __builtin_memcpy(&t[4 * j + 0], &b0, 2);
                __builtin_memcpy(&t[4 * j + 1], &b1, 2);
                __builtin_memcpy(&t[4 * j + 2], &b2, 2);
                __builtin_memcpy(&t[4 * j + 3], &b3, 2);
            }
            bv0 = *(const uint4*)&t[0];
            bv1 = *(const uint4*)&t[8];
        } else {
            const bf16* bg = (const bf16*)Bv + (long)(n0 + srow) * ldb + k0 + scol;
            bv0 = *(const uint4*)(bg);
            bv1 = *(const uint4*)(bg + 8);
        }
        __syncthreads();
        *(uint4*)&As[srow * LDST + scol] = av0;
        *(uint4*)&As[srow * LDST + scol + 8] = av1;
        *(uint4*)&Bs[srow * LDST + scol] = bv0;
        *(uint4*)&Bs[srow * LDST + scol + 8] = bv1;
        __syncthreads();

        s16x8 af[4], bfg[4];
#pragma unroll
        for (int mi = 0; mi < 4; mi++) {
            int r = wm * 64 + mi * 16 + lrow;
            af[mi] = *(const s16x8*)&As[r * LDST + quad * 8];
        }
#pragma unroll
        for (int ni = 0; ni < 4; ni++) {
            int r = wn * 64 + ni * 16 + lrow;
            bfg[ni] = *(const s16x8*)&Bs[r * LDST + quad * 8];
        }
#pragma unroll
        for (int mi = 0; mi < 4; mi++)
#pragma unroll
            for (int ni = 0; ni < 4; ni++)
                acc[mi][ni] = __builtin_amdgcn_mfma_f32_16x16x32_bf16(af[mi], bfg[ni], acc[mi][ni], 0, 0, 0);
    }

    // epilogue: C/D layout col = lane&15, row = quad*4 + i (content-verified r3≡r4)
#pragma unroll
    for (int mi = 0; mi < 4; mi++) {
#pragma unroll
        for (int ni = 0; ni < 4; ni++) {
            int col = n0 + wn * 64 + ni * 16 + lrow;
            float bv = bias ? bias[col] : 0.0f;
#pragma unroll
            for (int i = 0; i < 4; i++) {
                int row = m0 + wm * 64 + mi * 16 + quad * 4 + i;
                float v = accSign * acc[mi][ni][i] + bv;
                if (auxType == 1) v += ((const float*)aux)[(long)row * ldaux + col];
                else if (auxType == 2) v += (float)((const bf16*)aux)[(long)row * ldaux + col];
                if (relu) v = fmaxf(v, 0.0f);
                if (cF32) ((float*)C)[(long)row * ldc + col] = v;
                else ((bf16*)C)[(long)row * ldc + col] = (bf16)v;
            }
        }
    }
}

// ---------------- elementwise / normalization ----------------
__global__ __launch_bounds__(256) void l2norm_rows(bf16* __restrict__ Q) {
    bf16* q = Q + (long)blockIdx.x * KF;
    float v[4], ss = 0.0f;
#pragma unroll
    for (int i = 0; i < 4; i++) { v[i] = (float)q[threadIdx.x + i * 256]; ss += v[i] * v[i]; }
    ss = blockReduceSum(ss);
    float inv = 1.0f / fmaxf(sqrtf(ss), 1e-12f);
#pragma unroll
    for (int i = 0; i < 4; i++) q[threadIdx.x + i * 256] = (bf16)(v[i] * inv);
}

__global__ __launch_bounds__(256) void softmax_rows(bf16* __restrict__ P) {
    bf16* p = P + (long)blockIdx.x * LL;
    float v[8], mx = -1e30f;
#pragma unroll
    for (int i = 0; i < 8; i++) { v[i] = (float)p[threadIdx.x + i * 256]; mx = fmaxf(mx, v[i]); }
    mx = blockReduceMax(mx);
    float s = 0.0f;
#pragma unroll
    for (int i = 0; i < 8; i++) { v[i] = __expf(v[i] - mx); s += v[i]; }
    s = blockReduceSum(s);
    float inv = 1.0f / s;
#pragma unroll
    for (int i = 0; i < 8; i++) p[threadIdx.x + i * 256] = (bf16)(v[i] * inv);
}

__global__ __launch_bounds__(256) void zero_cs(float* __restrict__ cs) {
    cs[blockIdx.x * 256 + threadIdx.x] = 0.0f;
}

// Cs[col] += partial column sums (128 rows per block)
__global__ __launch_bounds__(256) void colsum_kernel(const bf16* __restrict__ P, float* __restrict__ cs) {
    int col = blockIdx.x * 256 + threadIdx.x;
    int r0 = blockIdx.y * 128;
    float s = 0.0f;
    for (int r = r0; r < r0 + 128; r++) s += (float)P[(long)r * LL + col];
    atomicAdd(&cs[col], s);
}

// fold query-renorm into V: Vt[e,m] /= (1e-9 + Cs[m])
__global__ __launch_bounds__(256) void scale_vt(bf16* __restrict__ vt, const float* __restrict__ cs) {
    int m = blockIdx.x * 256 + threadIdx.x;
    int e = blockIdx.y;
    long idx = (long)e * LL + m;
    vt[idx] = (bf16)((float)vt[idx] / (1e-9f + cs[m]));
}

// LN rows of 256: out = LN(in_bf16 [+aux_f32]) * g + b ; out bf16 or f32
__global__ __launch_bounds__(256) void ln_rows(const bf16* __restrict__ in, void* __restrict__ out,
                                               int outF32,
                                               const float* __restrict__ g, const float* __restrict__ b,
                                               const float* __restrict__ aux) {
    long base = (long)blockIdx.x * 256;
    float v = (float)in[base + threadIdx.x];
    if (aux) v += aux[base + threadIdx.x];
    float mean = blockReduceSum(v) * (1.0f / 256.0f);
    float d = v - mean;
    float var = blockReduceSum(d * d) * (1.0f / 256.0f);
    float o = d * rsqrtf(var + 1e-5f) * g[threadIdx.x] + b[threadIdx.x];
    if (outF32) ((float*)out)[base + threadIdx.x] = o;
    else ((bf16*)out)[base + threadIdx.x] = (bf16)o;
}

// ---------------- host ----------------
extern "C" void kernel_launch(void* const* d_in, const int* in_sizes, int n_in,
                              void* d_out, int out_size, void* d_ws, size_t ws_size,
                              hipStream_t stream) {
    const float* src  = (const float*)d_in[0];
    const float* WK   = (const float*)d_in[1];
    const float* WQ   = (const float*)d_in[2];
    const float* WV   = (const float*)d_in[3];
    const float* TC   = (const float*)d_in[4];
    const float* ENw1 = (const float*)d_in[5];
    const float* ENb1 = (const float*)d_in[6];
    const float* ENw2 = (const float*)d_in[7];
    const float* ENb2 = (const float*)d_in[8];
    const float* ENg  = (const float*)d_in[9];
    const float* ENbt = (const float*)d_in[10];
    const float* Wout = (const float*)d_in[11];
    const float* L1w  = (const float*)d_in[12];
    const float* L1b  = (const float*)d_in[13];
    const float* L2w  = (const float*)d_in[14];
    const float* L2b  = (const float*)d_in[15];
    const float* N1g  = (const float*)d_in[16];
    const float* N1b  = (const float*)d_in[17];
    const float* N2g  = (const float*)d_in[18];
    const float* N2b  = (const float*)d_in[19];

    // ---- diagnostics: ws floor / out_size / n_in ----
    const size_t FLOOR = 34700000;
    if (ws_size < FLOOR || out_size != NN * DM || n_in != 20) {
        float val;
        if (n_in != 20) val = 32768.0f + (float)n_in;
        else if (out_size != NN * DM) val = 49152.0f;
        else val = 16384.0f + 128.0f * (float)(unsigned)(ws_size >> 20);
        sentinel_kernel<<<1, 64, 0, stream>>>((float*)d_out, val);
        return;
    }

    char* w = (char*)d_ws;
    // compact slots (bytes) — total 34,611,200 (~33 MiB)
    bf16*  S0 = (bf16*)(w + 0);           // 16 MB: P / Hid / Ffh
    bf16*  S1 = (bf16*)(w + 16777216);    //  4 MB: Q / Ruh / Xb
    bf16*  S2 = (bf16*)(w + 20971520);    //  4 MB: K / tn / Yp
    bf16*  S3 = (bf16*)(w + 25165824);    //  1 MB: Vt
    bf16*  S4 = (bf16*)(w + 26214400);    //  4 MB: Su (L,B,D)
    bf16*  S5 = (bf16*)(w + 30408704);    //  4 MB: Xacc (N,D)
    float* Cs = (float*)(w + 34603008);   //  8 KB

    auto gemm = [&](const void* A, int aF32, int lda,
                    const void* B, int bF32, int ldb,
                    void* C, int cF32, int ldc, int M, int Nn, int Kc,
                    const float* bias, const void* aux, int auxType, int ldaux,
                    float accSign, int relu) {
        gemm_nt<<<dim3(M / 128, Nn / 128), dim3(256), 0, stream>>>(
            A, aF32, lda, B, bF32, ldb, C, cF32, ldc, Kc,
            bias, aux, auxType, ldaux, accSign, relu);
    };

    for (int h = 0; h < HN; h++) {
        for (int b = 0; b < BB; b++) {
            // Q = src_b @ WQ_h^T ; K = src_b @ WK_h^T   (2048x1024, Kc=256)
            gemm(src + b * DM, 1, BB * DM, WQ + (long)h * KF * DM, 1, DM,
                 S1, 0, KF, LL, KF, DM, nullptr, nullptr, 0, 0, 1.0f, 0);
            gemm(src + b * DM, 1, BB * DM, WK + (long)h * KF * DM, 1, DM,
                 S2, 0, KF, LL, KF, DM, nullptr, nullptr, 0, 0, 1.0f, 0);
            // Vt[e,l] = WV_h[e,:].src[l,b,:]   (256x2048, Kc=256)
            gemm(WV + (long)h * DM * DM, 1, DM, src + b * DM, 1, BB * DM,
                 S3, 0, LL, DM, LL, DM, nullptr, nullptr, 0, 0, 1.0f, 0);
            l2norm_rows<<<LL, 256, 0, stream>>>(S1);
            l2norm_rows<<<LL, 256, 0, stream>>>(S2);
            // P = Q @ K^T   (2048x2048, Kc=1024)
            gemm(S1, 0, KF, S2, 0, KF, S0, 0, LL, LL, LL, KF,
                 nullptr, nullptr, 0, 0, 1.0f, 0);
            softmax_rows<<<LL, 256, 0, stream>>>(S0);
            zero_cs<<<LL / 256, 256, 0, stream>>>(Cs);
            colsum_kernel<<<dim3(LL / 256, LL / 128), 256, 0, stream>>>(S0, Cs);
            scale_vt<<<dim3(LL / 256, DM), 256, 0, stream>>>(S3, Cs);
            // Su[l,b,:] = src[l,b,:] - P @ Vt'   (2048x256, Kc=2048)
            gemm(S0, 0, LL, S3, 0, LL, S4 + b * DM, 0, BB * DM, LL, DM, LL,
                 nullptr, src + b * DM, 1, BB * DM, -1.0f, 0);
        }
        // Ruh = relu(Su @ TC_h^T)   (8192x256, Kc=256)
        gemm(S4, 0, DM, TC + (long)h * DM * DM, 1, DM, S1, 0, DM, NN, DM, DM,
             nullptr, nullptr, 0, 0, 1.0f, 1);
        // Hid = relu(Ruh @ ENw1_h^T + b1)   (8192x1024, Kc=256)
        gemm(S1, 0, DM, ENw1 + (long)h * FFD * DM, 1, DM, S0, 0, FFD, NN, FFD, DM,
             ENb1 + (long)h * FFD, nullptr, 0, 0, 1.0f, 1);
        // tn_pre = Hid @ ENw2_h^T + b2 + Ruh   (8192x256, Kc=1024)
        gemm(S0, 0, FFD, ENw2 + (long)h * DM * FFD, 1, FFD, S2, 0, DM, NN, DM, FFD,
             ENb2 + (long)h * DM, S1, 2, DM, 1.0f, 0);
        // tn = per-head LN (in place)
        ln_rows<<<NN, 256, 0, stream>>>(S2, S2, 0, ENg + (long)h * DM, ENbt + (long)h * DM, nullptr);
        // Xacc (+)= tn @ Wout_h^T   (8192x256, Kc=256)
        gemm(S2, 0, DM, Wout + (long)h * DM, 1, HD, S5, 0, DM, NN, DM, DM,
             nullptr, (h == 0) ? nullptr : (const void*)S5, (h == 0) ? 0 : 2, DM, 1.0f, 0);
    }

    // x = LN(src + attn) -> S1 ; FFN ; final LN -> d_out (f32!)
    ln_rows<<<NN, 256, 0, stream>>>(S5, S1, 0, N1g, N1b, src);
    gemm(S1, 0, DM, L1w, 1, DM, S0, 0, FFD, NN, FFD, DM,
         L1b, nullptr, 0, 0, 1.0f, 1);
    gemm(S0, 0, FFD, L2w, 1, FFD, S2, 0, DM, NN, DM, FFD,
         L2b, S1, 2, DM, 1.0f, 0);
    ln_rows<<<NN, 256, 0, stream>>>(S2, (float*)d_out, 1, N2g, N2b, nullptr);
}

// Round 9
// 1690.835 us; speedup vs baseline: 1.9662x; 1.9662x over previous
//
#include <hip/hip_runtime.h>
#include <hip/hip_bf16.h>

typedef __hip_bfloat16 bf16;
typedef short s16x8 __attribute__((ext_vector_type(8)));
typedef float f32x4 __attribute__((ext_vector_type(4)));

#ifndef __has_builtin
#define __has_builtin(x) 0
#endif
#if __has_builtin(__builtin_amdgcn_global_load_lds)
#define HAS_GLL 1
#else
#define HAS_GLL 0
#endif

// Problem constants
#define HN 4
#define DM 256
#define KF 1024
#define FFD 1024
#define LL 2048
#define BB 4
#define NN (LL * BB)   // 8192
#define HD (HN * DM)   // 1024

__device__ __forceinline__ float b2f(unsigned short u) {
    unsigned v = ((unsigned)u) << 16; float f; __builtin_memcpy(&f, &v, 4); return f;
}
__device__ __forceinline__ unsigned short f2b(float f) {
    bf16 b = (bf16)f; unsigned short u; __builtin_memcpy(&u, &b, 2); return u;
}

// ---------------- reductions ----------------
__device__ __forceinline__ float waveReduceSum(float v) {
    for (int o = 32; o; o >>= 1) v += __shfl_down(v, o, 64);
    return v;
}
__device__ __forceinline__ float waveReduceMax(float v) {
    for (int o = 32; o; o >>= 1) v = fmaxf(v, __shfl_down(v, o, 64));
    return v;
}
__device__ __forceinline__ float blockReduceSum(float v) {
    __shared__ float sh[4];
    v = waveReduceSum(v);
    __syncthreads();
    if ((threadIdx.x & 63) == 0) sh[threadIdx.x >> 6] = v;
    __syncthreads();
    return sh[0] + sh[1] + sh[2] + sh[3];
}
__device__ __forceinline__ float blockReduceMax(float v) {
    __shared__ float sh[4];
    v = waveReduceMax(v);
    __syncthreads();
    if ((threadIdx.x & 63) == 0) sh[threadIdx.x >> 6] = v;
    __syncthreads();
    return fmaxf(fmaxf(sh[0], sh[1]), fmaxf(sh[2], sh[3]));
}

__global__ void sentinel_kernel(float* out, float val) {
    if (threadIdx.x == 0 && blockIdx.x == 0) out[0] = val;
}

#if HAS_GLL
__device__ __forceinline__ void gll16(void* g, void* l) {
    __builtin_amdgcn_global_load_lds(
        (__attribute__((address_space(1))) unsigned int*)g,
        (__attribute__((address_space(3))) unsigned int*)l, 16, 0, 0);
}
#endif

// ---------------- MFMA GEMM ----------------
// C = accSign*(A @ B^T) [+bias[col]] [+aux] [relu], batched over grid.z.
// aF32/bF32: operand dtype (f32 converted at staging; bf16 staged via global_load_lds).
// LDS tiles 128x32 bf16 unpadded (global_load_lds-compatible).
__global__ __launch_bounds__(256) void gemm_nt(
    const void* __restrict__ A, int aF32, int lda, long sA,
    const void* __restrict__ Bv, int bF32, int ldb, long sB,
    void* __restrict__ C, int cF32, int ldc, long sC,
    int Kc,
    const float* __restrict__ bias, long sBias,
    const void* __restrict__ aux, int auxType, int ldaux, long sAux,
    float accSign, int relu)
{
    const int z = blockIdx.z;
    const float* Af = (const float*)A + (long)z * sA;
    const bf16*  Ah = (const bf16*)A + (long)z * sA;
    const float* Bf = (const float*)Bv + (long)z * sB;
    const bf16*  Bh = (const bf16*)Bv + (long)z * sB;
    float* Cf = (float*)C + (long)z * sC;
    bf16*  Ch = (bf16*)C + (long)z * sC;
    const float* biasp = bias ? (bias + (long)z * sBias) : nullptr;
    const float* auxf = (auxType == 1) ? ((const float*)aux + (long)z * sAux) : nullptr;
    const bf16*  auxh = (auxType == 2) ? ((const bf16*)aux + (long)z * sAux) : nullptr;

    __shared__ __align__(16) bf16 As[128 * 32];
    __shared__ __align__(16) bf16 Bs[128 * 32];

    const int tid = threadIdx.x;
    const int lane = tid & 63;
    const int wv = __builtin_amdgcn_readfirstlane(tid >> 6);
    const int wm = (tid >> 6) & 1;
    const int wn = (tid >> 6) >> 1;
    const int lrow = lane & 15;
    const int quad = lane >> 4;
    const int m0 = blockIdx.x * 128;
    const int n0 = blockIdx.y * 128;
    const int srow = tid >> 1;         // f32-staging: 0..127
    const int scol = (tid & 1) * 16;   // 0 or 16
    const int drow = wv * 16 + (lane >> 2);   // GLL: row within 64-row half
    const int dcol = (lane & 3) * 8;          // GLL: col chunk (8 bf16 = 16 B)

    f32x4 acc[4][4] = {};

    for (int k0 = 0; k0 < Kc; k0 += 32) {
        uint4 av0, av1, bv0, bv1;
        if (aF32) {
            const float* ag = Af + (long)(m0 + srow) * lda + k0 + scol;
            ushort t[16];
#pragma unroll
            for (int j = 0; j < 4; j++) {
                float4 f = *(const float4*)(ag + 4 * j);
                t[4*j] = f2b(f.x); t[4*j+1] = f2b(f.y); t[4*j+2] = f2b(f.z); t[4*j+3] = f2b(f.w);
            }
            av0 = *(const uint4*)&t[0]; av1 = *(const uint4*)&t[8];
        }
#if !HAS_GLL
        else {
            const bf16* ag = Ah + (long)(m0 + srow) * lda + k0 + scol;
            av0 = *(const uint4*)ag; av1 = *(const uint4*)(ag + 8);
        }
#endif
        if (bF32) {
            const float* bg = Bf + (long)(n0 + srow) * ldb + k0 + scol;
            ushort t[16];
#pragma unroll
            for (int j = 0; j < 4; j++) {
                float4 f = *(const float4*)(bg + 4 * j);
                t[4*j] = f2b(f.x); t[4*j+1] = f2b(f.y); t[4*j+2] = f2b(f.z); t[4*j+3] = f2b(f.w);
            }
            bv0 = *(const uint4*)&t[0]; bv1 = *(const uint4*)&t[8];
        }
#if !HAS_GLL
        else {
            const bf16* bg = Bh + (long)(n0 + srow) * ldb + k0 + scol;
            bv0 = *(const uint4*)bg; bv1 = *(const uint4*)(bg + 8);
        }
#endif
        __syncthreads();
        if (aF32) {
            *(uint4*)&As[srow * 32 + scol] = av0;
            *(uint4*)&As[srow * 32 + scol + 8] = av1;
        } else {
#if HAS_GLL
            gll16((void*)(Ah + (long)(m0 + drow) * lda + k0 + dcol), (void*)(As + wv * 512));
            gll16((void*)(Ah + (long)(m0 + 64 + drow) * lda + k0 + dcol), (void*)(As + 2048 + wv * 512));
#else
            *(uint4*)&As[srow * 32 + scol] = av0;
            *(uint4*)&As[srow * 32 + scol + 8] = av1;
#endif
        }
        if (bF32) {
            *(uint4*)&Bs[srow * 32 + scol] = bv0;
            *(uint4*)&Bs[srow * 32 + scol + 8] = bv1;
        } else {
#if HAS_GLL
            gll16((void*)(Bh + (long)(n0 + drow) * ldb + k0 + dcol), (void*)(Bs + wv * 512));
            gll16((void*)(Bh + (long)(n0 + 64 + drow) * ldb + k0 + dcol), (void*)(Bs + 2048 + wv * 512));
#else
            *(uint4*)&Bs[srow * 32 + scol] = bv0;
            *(uint4*)&Bs[srow * 32 + scol + 8] = bv1;
#endif
        }
        __syncthreads();

        s16x8 af[4], bfg[4];
#pragma unroll
        for (int mi = 0; mi < 4; mi++) {
            int r = wm * 64 + mi * 16 + lrow;
            af[mi] = *(const s16x8*)&As[r * 32 + quad * 8];
        }
#pragma unroll
        for (int ni = 0; ni < 4; ni++) {
            int r = wn * 64 + ni * 16 + lrow;
            bfg[ni] = *(const s16x8*)&Bs[r * 32 + quad * 8];
        }
#pragma unroll
        for (int mi = 0; mi < 4; mi++)
#pragma unroll
            for (int ni = 0; ni < 4; ni++)
                acc[mi][ni] = __builtin_amdgcn_mfma_f32_16x16x32_bf16(af[mi], bfg[ni], acc[mi][ni], 0, 0, 0);
    }

    // epilogue: C/D layout col = lane&15, row = quad*4 + i (verified)
#pragma unroll
    for (int mi = 0; mi < 4; mi++) {
#pragma unroll
        for (int ni = 0; ni < 4; ni++) {
            int col = n0 + wn * 64 + ni * 16 + lrow;
            float bv = biasp ? biasp[col] : 0.0f;
#pragma unroll
            for (int i = 0; i < 4; i++) {
                int row = m0 + wm * 64 + mi * 16 + quad * 4 + i;
                float v = accSign * acc[mi][ni][i] + bv;
                if (auxType == 1) v += auxf[(long)row * ldaux + col];
                else if (auxType == 2) v += (float)auxh[(long)row * ldaux + col];
                if (relu) v = fmaxf(v, 0.0f);
                if (cF32) Cf[(long)row * ldc + col] = v;
                else Ch[(long)row * ldc + col] = (bf16)v;
            }
        }
    }
}

// ---------------- elementwise / normalization ----------------
__global__ __launch_bounds__(256) void cvt4(const float* __restrict__ in, bf16* __restrict__ out, int n4) {
    int i = blockIdx.x * 256 + threadIdx.x;
    if (i < n4) {
        float4 f = ((const float4*)in)[i];
        ushort4 u; u.x = f2b(f.x); u.y = f2b(f.y); u.z = f2b(f.z); u.w = f2b(f.w);
        ((ushort4*)out)[i] = u;
    }
}

// in-place L2 normalize bf16 rows of length KF (vectorized)
__global__ __launch_bounds__(256) void l2norm_rows(bf16* __restrict__ Q) {
    bf16* q = Q + (long)blockIdx.x * KF;
    ushort4 u = ((ushort4*)q)[threadIdx.x];
    float v0 = b2f(u.x), v1 = b2f(u.y), v2 = b2f(u.z), v3 = b2f(u.w);
    float ss = blockReduceSum(v0 * v0 + v1 * v1 + v2 * v2 + v3 * v3);
    float inv = 1.0f / fmaxf(sqrtf(ss), 1e-12f);
    u.x = f2b(v0 * inv); u.y = f2b(v1 * inv); u.z = f2b(v2 * inv); u.w = f2b(v3 * inv);
    ((ushort4*)q)[threadIdx.x] = u;
}

// in-place softmax over bf16 rows of length LL (vectorized)
__global__ __launch_bounds__(256) void softmax_rows(bf16* __restrict__ P) {
    bf16* p = P + (long)blockIdx.x * LL;
    ushort4 a = ((ushort4*)p)[2 * threadIdx.x];
    ushort4 b = ((ushort4*)p)[2 * threadIdx.x + 1];
    float v[8] = {b2f(a.x), b2f(a.y), b2f(a.z), b2f(a.w), b2f(b.x), b2f(b.y), b2f(b.z), b2f(b.w)};
    float mx = -1e30f;
#pragma unroll
    for (int i = 0; i < 8; i++) mx = fmaxf(mx, v[i]);
    mx = blockReduceMax(mx);
    float s = 0.0f;
#pragma unroll
    for (int i = 0; i < 8; i++) { v[i] = __expf(v[i] - mx); s += v[i]; }
    s = blockReduceSum(s);
    float inv = 1.0f / s;
    a.x = f2b(v[0]*inv); a.y = f2b(v[1]*inv); a.z = f2b(v[2]*inv); a.w = f2b(v[3]*inv);
    b.x = f2b(v[4]*inv); b.y = f2b(v[5]*inv); b.z = f2b(v[6]*inv); b.w = f2b(v[7]*inv);
    ((ushort4*)p)[2 * threadIdx.x] = a;
    ((ushort4*)p)[2 * threadIdx.x + 1] = b;
}

// Cs[b][col] = sum_r P[b][r][col]   grid (LL/256, nb)
__global__ __launch_bounds__(256) void colsum_kernel(const bf16* __restrict__ P, float* __restrict__ cs) {
    int col = blockIdx.x * 256 + threadIdx.x;
    int b = blockIdx.y;
    const bf16* p = P + (long)b * LL * LL + col;
    float s = 0.0f;
    for (int r = 0; r < LL; r++) s += (float)p[(long)r * LL];
    cs[(long)b * LL + col] = s;
}

// Vt[b][e][m] /= (1e-9 + Cs[b][m])   grid (DM, nb)
__global__ __launch_bounds__(256) void scale_vt(bf16* __restrict__ vt, const float* __restrict__ cs) {
    int e = blockIdx.x, b = blockIdx.y;
    bf16* row = vt + ((long)b * DM + e) * LL;
    const float* c = cs + (long)b * LL;
#pragma unroll
    for (int i = 0; i < 8; i++) {
        int m = threadIdx.x + i * 256;
        row[m] = (bf16)((float)row[m] / (1e-9f + c[m]));
    }
}

// LN rows of 256: out = LN(in_bf16 [+aux_f32]) * g + b ; out bf16 or f32
__global__ __launch_bounds__(256) void ln_rows(const bf16* __restrict__ in, void* __restrict__ out,
                                               int outF32,
                                               const float* __restrict__ g, const float* __restrict__ b,
                                               const float* __restrict__ aux) {
    long base = (long)blockIdx.x * 256;
    float v = (float)in[base + threadIdx.x];
    if (aux) v += aux[base + threadIdx.x];
    float mean = blockReduceSum(v) * (1.0f / 256.0f);
    float d = v - mean;
    float var = blockReduceSum(d * d) * (1.0f / 256.0f);
    float o = d * rsqrtf(var + 1e-5f) * g[threadIdx.x] + b[threadIdx.x];
    if (outF32) ((float*)out)[base + threadIdx.x] = o;
    else ((bf16*)out)[base + threadIdx.x] = (bf16)o;
}

// per-head LN on Cat layout: row n, head h at n*HD + h*DM, in place
__global__ __launch_bounds__(256) void ln_cat(bf16* __restrict__ cat, const float* __restrict__ g,
                                              const float* __restrict__ bb) {
    long n = blockIdx.x;
    int h = blockIdx.y;
    bf16* x = cat + n * HD + (long)h * DM;
    float v = (float)x[threadIdx.x];
    float mean = blockReduceSum(v) * (1.0f / 256.0f);
    float d = v - mean;
    float var = blockReduceSum(d * d) * (1.0f / 256.0f);
    x[threadIdx.x] = (bf16)(d * rsqrtf(var + 1e-5f) * g[h * DM + threadIdx.x] + bb[h * DM + threadIdx.x]);
}

// ---------------- host ----------------
extern "C" void kernel_launch(void* const* d_in, const int* in_sizes, int n_in,
                              void* d_out, int out_size, void* d_ws, size_t ws_size,
                              hipStream_t stream) {
    const float* src  = (const float*)d_in[0];
    const float* WK   = (const float*)d_in[1];
    const float* WQ   = (const float*)d_in[2];
    const float* WV   = (const float*)d_in[3];
    const float* TC   = (const float*)d_in[4];
    const float* ENw1 = (const float*)d_in[5];
    const float* ENb1 = (const float*)d_in[6];
    const float* ENw2 = (const float*)d_in[7];
    const float* ENb2 = (const float*)d_in[8];
    const float* ENg  = (const float*)d_in[9];
    const float* ENbt = (const float*)d_in[10];
    const float* Wout = (const float*)d_in[11];
    const float* L1w  = (const float*)d_in[12];
    const float* L1b  = (const float*)d_in[13];
    const float* L2w  = (const float*)d_in[14];
    const float* L2b  = (const float*)d_in[15];
    const float* N1g  = (const float*)d_in[16];
    const float* N1b  = (const float*)d_in[17];
    const float* N2g  = (const float*)d_in[18];
    const float* N2b  = (const float*)d_in[19];

    const size_t COMPACT_FLOOR = 34700000;
    const size_t FAST_FLOOR = 92307456;
    if (ws_size < COMPACT_FLOOR || out_size != NN * DM || n_in != 20) {
        float val;
        if (n_in != 20) val = 32768.0f + (float)n_in;
        else if (out_size != NN * DM) val = 49152.0f;
        else val = 16384.0f + 128.0f * (float)(unsigned)(ws_size >> 20);
        sentinel_kernel<<<1, 64, 0, stream>>>((float*)d_out, val);
        return;
    }

    char* w = (char*)d_ws;
    auto G = [&](const void* A, int aF, int lda, long sA,
                 const void* B, int bF, int ldb, long sB,
                 void* C, int cF, int ldc, long sC,
                 int M, int Nn, int Kc, int nb,
                 const float* bias, long sBias,
                 const void* aux, int auxT, int ldaux, long sAux,
                 float sgn, int relu) {
        gemm_nt<<<dim3(M / 128, Nn / 128, nb), dim3(256), 0, stream>>>(
            A, aF, lda, sA, B, bF, ldb, sB, C, cF, ldc, sC, Kc,
            bias, sBias, aux, auxT, ldaux, sAux, sgn, relu);
    };

    if (ws_size >= FAST_FLOOR) {
        // ======== FAST PATH (92.3 MB) ========
        bf16*  Sb  = (bf16*)(w + 0);           //  4 MB src bf16
        bf16*  Q   = (bf16*)(w + 4194304);     // 16 MB  (alias: Ru, Ffh)
        bf16*  K   = (bf16*)(w + 20971520);    // 16 MB  (alias: Hid)
        bf16*  Vt  = (bf16*)(w + 37748736);    //  4 MB  (alias: Attn, Yp)
        bf16*  P   = (bf16*)(w + 41943040);    // 32 MB  (alias: Cat)
        bf16*  Su  = (bf16*)(w + 75497472);    // 16 MB  (alias: Xln)
        float* Cs  = (float*)(w + 92274688);   // 32 KB
        bf16* Ru = Q; bf16* Hid = K; bf16* Cat = P;
        bf16* Attn = Vt; bf16* Xln = Su; bf16* Ffh = Q; bf16* Yp = Vt;

        cvt4<<<2048, 256, 0, stream>>>(src, Sb, NN * DM / 4);

        for (int h = 0; h < HN; h++) {
            // Q/K: (8192 x 1024, Kc=256)
            G(Sb, 0, DM, 0, WQ + (long)h * KF * DM, 1, DM, 0, Q, 0, KF, 0,
              NN, KF, DM, 1, nullptr, 0, nullptr, 0, 0, 0, 1.0f, 0);
            G(Sb, 0, DM, 0, WK + (long)h * KF * DM, 1, DM, 0, K, 0, KF, 0,
              NN, KF, DM, 1, nullptr, 0, nullptr, 0, 0, 0, 1.0f, 0);
            // Vt[b][e][l], z=b: (256 x 2048, Kc=256)
            G(WV + (long)h * DM * DM, 1, DM, 0, Sb, 0, BB * DM, DM, Vt, 0, LL, (long)DM * LL,
              DM, LL, DM, BB, nullptr, 0, nullptr, 0, 0, 0, 1.0f, 0);
            l2norm_rows<<<NN, 256, 0, stream>>>(Q);
            l2norm_rows<<<NN, 256, 0, stream>>>(K);
            // P[b] = Q_b @ K_b^T, z=b: (2048 x 2048, Kc=1024)
            G(Q, 0, BB * KF, KF, K, 0, BB * KF, KF, P, 0, LL, (long)LL * LL,
              LL, LL, KF, BB, nullptr, 0, nullptr, 0, 0, 0, 1.0f, 0);
            softmax_rows<<<BB * LL, 256, 0, stream>>>(P);
            colsum_kernel<<<dim3(LL / 256, BB), 256, 0, stream>>>(P, Cs);
            scale_vt<<<dim3(DM, BB), 256, 0, stream>>>(Vt, Cs);
            // Su[h] = src - P@Vt', z=b: (2048 x 256, Kc=2048)
            G(P, 0, LL, (long)LL * LL, Vt, 0, LL, (long)DM * LL,
              Su + (long)h * NN * DM, 0, BB * DM, DM,
              LL, DM, LL, BB, nullptr, 0, Sb, 2, BB * DM, DM, -1.0f, 0);
        }
        // TC batched z=h: (8192 x 256, Kc=256)
        G(Su, 0, DM, (long)NN * DM, TC, 1, DM, (long)DM * DM, Ru, 0, DM, (long)NN * DM,
          NN, DM, DM, HN, nullptr, 0, nullptr, 0, 0, 0, 1.0f, 1);
        for (int h = 0; h < HN; h++) {
            G(Ru + (long)h * NN * DM, 0, DM, 0, ENw1 + (long)h * FFD * DM, 1, DM, 0,
              Hid, 0, FFD, 0, NN, FFD, DM, 1, ENb1 + (long)h * FFD, 0, nullptr, 0, 0, 0, 1.0f, 1);
            G(Hid, 0, FFD, 0, ENw2 + (long)h * DM * FFD, 1, FFD, 0,
              Cat + (long)h * DM, 0, HD, 0, NN, DM, FFD, 1,
              ENb2 + (long)h * DM, 0, Ru + (long)h * NN * DM, 2, DM, 0, 1.0f, 0);
        }
        ln_cat<<<dim3(NN, HN), 256, 0, stream>>>(Cat, ENg, ENbt);
        // attn = Cat @ Wout^T: (8192 x 256, Kc=1024)
        G(Cat, 0, HD, 0, Wout, 1, HD, 0, Attn, 0, DM, 0,
          NN, DM, HD, 1, nullptr, 0, nullptr, 0, 0, 0, 1.0f, 0);
        ln_rows<<<NN, 256, 0, stream>>>(Attn, Xln, 0, N1g, N1b, src);
        G(Xln, 0, DM, 0, L1w, 1, DM, 0, Ffh, 0, FFD, 0,
          NN, FFD, DM, 1, L1b, 0, nullptr, 0, 0, 0, 1.0f, 1);
        G(Ffh, 0, FFD, 0, L2w, 1, FFD, 0, Yp, 0, DM, 0,
          NN, DM, FFD, 1, L2b, 0, Xln, 2, DM, 0, 1.0f, 0);
        ln_rows<<<NN, 256, 0, stream>>>(Yp, (float*)d_out, 1, N2g, N2b, nullptr);
    } else {
        // ======== COMPACT PATH (round-8 verified sequence, 34.7 MB) ========
        bf16*  S0 = (bf16*)(w + 0);
        bf16*  S1 = (bf16*)(w + 16777216);
        bf16*  S2 = (bf16*)(w + 20971520);
        bf16*  S3 = (bf16*)(w + 25165824);
        bf16*  S4 = (bf16*)(w + 26214400);
        bf16*  S5 = (bf16*)(w + 30408704);
        float* Cs = (float*)(w + 34603008);

        for (int h = 0; h < HN; h++) {
            for (int b = 0; b < BB; b++) {
                G(src + b * DM, 1, BB * DM, 0, WQ + (long)h * KF * DM, 1, DM, 0,
                  S1, 0, KF, 0, LL, KF, DM, 1, nullptr, 0, nullptr, 0, 0, 0, 1.0f, 0);
                G(src + b * DM, 1, BB * DM, 0, WK + (long)h * KF * DM, 1, DM, 0,
                  S2, 0, KF, 0, LL, KF, DM, 1, nullptr, 0, nullptr, 0, 0, 0, 1.0f, 0);
                G(WV + (long)h * DM * DM, 1, DM, 0, src + b * DM, 1, BB * DM, 0,
                  S3, 0, LL, 0, DM, LL, DM, 1, nullptr, 0, nullptr, 0, 0, 0, 1.0f, 0);
                l2norm_rows<<<LL, 256, 0, stream>>>(S1);
                l2norm_rows<<<LL, 256, 0, stream>>>(S2);
                G(S1, 0, KF, 0, S2, 0, KF, 0, S0, 0, LL, 0,
                  LL, LL, KF, 1, nullptr, 0, nullptr, 0, 0, 0, 1.0f, 0);
                softmax_rows<<<LL, 256, 0, stream>>>(S0);
                colsum_kernel<<<dim3(LL / 256, 1), 256, 0, stream>>>(S0, Cs);
                scale_vt<<<dim3(DM, 1), 256, 0, stream>>>(S3, Cs);
                G(S0, 0, LL, 0, S3, 0, LL, 0, S4 + b * DM, 0, BB * DM, 0,
                  LL, DM, LL, 1, nullptr, 0, src + b * DM, 1, BB * DM, 0, -1.0f, 0);
            }
            G(S4, 0, DM, 0, TC + (long)h * DM * DM, 1, DM, 0, S1, 0, DM, 0,
              NN, DM, DM, 1, nullptr, 0, nullptr, 0, 0, 0, 1.0f, 1);
            G(S1, 0, DM, 0, ENw1 + (long)h * FFD * DM, 1, DM, 0, S0, 0, FFD, 0,
              NN, FFD, DM, 1, ENb1 + (long)h * FFD, 0, nullptr, 0, 0, 0, 1.0f, 1);
            G(S0, 0, FFD, 0, ENw2 + (long)h * DM * FFD, 1, FFD, 0, S2, 0, DM, 0,
              NN, DM, FFD, 1, ENb2 + (long)h * DM, 0, S1, 2, DM, 0, 1.0f, 0);
            ln_rows<<<NN, 256, 0, stream>>>(S2, S2, 0, ENg + (long)h * DM, ENbt + (long)h * DM, nullptr);
            G(S2, 0, DM, 0, Wout + (long)h * DM, 1, HD, 0, S5, 0, DM, 0,
              NN, DM, DM, 1, nullptr, 0, (h == 0) ? nullptr : (const void*)S5,
              (h == 0) ? 0 : 2, DM, 0, 1.0f, 0);
        }
        ln_rows<<<NN, 256, 0, stream>>>(S5, S1, 0, N1g, N1b, src);
        G(S1, 0, DM, 0, L1w, 1, DM, 0, S0, 0, FFD, 0,
          NN, FFD, DM, 1, L1b, 0, nullptr, 0, 0, 0, 1.0f, 1);
        G(S0, 0, FFD, 0, L2w, 1, FFD, 0, S2, 0, DM, 0,
          NN, DM, FFD, 1, L2b, 0, S1, 2, DM, 0, 1.0f, 0);
        ln_rows<<<NN, 256, 0, stream>>>(S2, (float*)d_out, 1, N2g, N2b, nullptr);
    }
}

// Round 10
// 1281.363 us; speedup vs baseline: 2.5945x; 1.3196x over previous
//
#include <hip/hip_runtime.h>
#include <hip/hip_bf16.h>

typedef __hip_bfloat16 bf16;
typedef short s16x8 __attribute__((ext_vector_type(8)));
typedef float f32x4 __attribute__((ext_vector_type(4)));

#ifndef __has_builtin
#define __has_builtin(x) 0
#endif
#if __has_builtin(__builtin_amdgcn_global_load_lds)
#define HAS_GLL 1
#else
#define HAS_GLL 0
#endif

// Problem constants
#define HN 4
#define DM 256
#define KF 1024
#define FFD 1024
#define LL 2048
#define BB 4
#define NN (LL * BB)   // 8192
#define HD (HN * DM)   // 1024

__device__ __forceinline__ float b2f(unsigned short u) {
    unsigned v = ((unsigned)u) << 16; float f; __builtin_memcpy(&f, &v, 4); return f;
}
__device__ __forceinline__ unsigned short f2b(float f) {
    bf16 b = (bf16)f; unsigned short u; __builtin_memcpy(&u, &b, 2); return u;
}

// ---------------- reductions ----------------
__device__ __forceinline__ float waveReduceSum(float v) {
    for (int o = 32; o; o >>= 1) v += __shfl_down(v, o, 64);
    return v;
}
__device__ __forceinline__ float waveReduceMax(float v) {
    for (int o = 32; o; o >>= 1) v = fmaxf(v, __shfl_down(v, o, 64));
    return v;
}
__device__ __forceinline__ float blockReduceSum(float v) {
    __shared__ float sh[4];
    v = waveReduceSum(v);
    __syncthreads();
    if ((threadIdx.x & 63) == 0) sh[threadIdx.x >> 6] = v;
    __syncthreads();
    return sh[0] + sh[1] + sh[2] + sh[3];
}
__device__ __forceinline__ float blockReduceMax(float v) {
    __shared__ float sh[4];
    v = waveReduceMax(v);
    __syncthreads();
    if ((threadIdx.x & 63) == 0) sh[threadIdx.x >> 6] = v;
    __syncthreads();
    return fmaxf(fmaxf(sh[0], sh[1]), fmaxf(sh[2], sh[3]));
}

__global__ void sentinel_kernel(float* out, float val) {
    if (threadIdx.x == 0 && blockIdx.x == 0) out[0] = val;
}

#if HAS_GLL
__device__ __forceinline__ void gll16(void* g, void* l) {
    __builtin_amdgcn_global_load_lds(
        (__attribute__((address_space(1))) unsigned int*)g,
        (__attribute__((address_space(3))) unsigned int*)l, 16, 0, 0);
}
#endif

// ---------------- MFMA GEMM ----------------
// C = accSign*(A @ B^T) [+bias[col]] [+aux] [relu], batched over grid.z.
// aF32/bF32: operand dtype (f32 converted at staging; bf16 staged via global_load_lds).
__global__ __launch_bounds__(256) void gemm_nt(
    const void* __restrict__ A, int aF32, int lda, long sA,
    const void* __restrict__ Bv, int bF32, int ldb, long sB,
    void* __restrict__ C, int cF32, int ldc, long sC,
    int Kc,
    const float* __restrict__ bias, long sBias,
    const void* __restrict__ aux, int auxType, int ldaux, long sAux,
    float accSign, int relu)
{
    const int z = blockIdx.z;
    const float* Af = (const float*)A + (long)z * sA;
    const bf16*  Ah = (const bf16*)A + (long)z * sA;
    const float* Bf = (const float*)Bv + (long)z * sB;
    const bf16*  Bh = (const bf16*)Bv + (long)z * sB;
    float* Cf = (float*)C + (long)z * sC;
    bf16*  Ch = (bf16*)C + (long)z * sC;
    const float* biasp = bias ? (bias + (long)z * sBias) : nullptr;
    const float* auxf = (auxType == 1) ? ((const float*)aux + (long)z * sAux) : nullptr;
    const bf16*  auxh = (auxType == 2) ? ((const bf16*)aux + (long)z * sAux) : nullptr;

    __shared__ __align__(16) bf16 As[128 * 32];
    __shared__ __align__(16) bf16 Bs[128 * 32];

    const int tid = threadIdx.x;
    const int lane = tid & 63;
    const int wv = __builtin_amdgcn_readfirstlane(tid >> 6);
    const int wm = (tid >> 6) & 1;
    const int wn = (tid >> 6) >> 1;
    const int lrow = lane & 15;
    const int quad = lane >> 4;
    const int m0 = blockIdx.x * 128;
    const int n0 = blockIdx.y * 128;
    const int srow = tid >> 1;
    const int scol = (tid & 1) * 16;
    const int drow = wv * 16 + (lane >> 2);
    const int dcol = (lane & 3) * 8;

    f32x4 acc[4][4] = {};

    for (int k0 = 0; k0 < Kc; k0 += 32) {
        uint4 av0, av1, bv0, bv1;
        if (aF32) {
            const float* ag = Af + (long)(m0 + srow) * lda + k0 + scol;
            ushort t[16];
#pragma unroll
            for (int j = 0; j < 4; j++) {
                float4 f = *(const float4*)(ag + 4 * j);
                t[4*j] = f2b(f.x); t[4*j+1] = f2b(f.y); t[4*j+2] = f2b(f.z); t[4*j+3] = f2b(f.w);
            }
            av0 = *(const uint4*)&t[0]; av1 = *(const uint4*)&t[8];
        }
#if !HAS_GLL
        else {
            const bf16* ag = Ah + (long)(m0 + srow) * lda + k0 + scol;
            av0 = *(const uint4*)ag; av1 = *(const uint4*)(ag + 8);
        }
#endif
        if (bF32) {
            const float* bg = Bf + (long)(n0 + srow) * ldb + k0 + scol;
            ushort t[16];
#pragma unroll
            for (int j = 0; j < 4; j++) {
                float4 f = *(const float4*)(bg + 4 * j);
                t[4*j] = f2b(f.x); t[4*j+1] = f2b(f.y); t[4*j+2] = f2b(f.z); t[4*j+3] = f2b(f.w);
            }
            bv0 = *(const uint4*)&t[0]; bv1 = *(const uint4*)&t[8];
        }
#if !HAS_GLL
        else {
            const bf16* bg = Bh + (long)(n0 + srow) * ldb + k0 + scol;
            bv0 = *(const uint4*)bg; bv1 = *(const uint4*)(bg + 8);
        }
#endif
        __syncthreads();
        if (aF32) {
            *(uint4*)&As[srow * 32 + scol] = av0;
            *(uint4*)&As[srow * 32 + scol + 8] = av1;
        } else {
#if HAS_GLL
            gll16((void*)(Ah + (long)(m0 + drow) * lda + k0 + dcol), (void*)(As + wv * 512));
            gll16((void*)(Ah + (long)(m0 + 64 + drow) * lda + k0 + dcol), (void*)(As + 2048 + wv * 512));
#else
            *(uint4*)&As[srow * 32 + scol] = av0;
            *(uint4*)&As[srow * 32 + scol + 8] = av1;
#endif
        }
        if (bF32) {
            *(uint4*)&Bs[srow * 32 + scol] = bv0;
            *(uint4*)&Bs[srow * 32 + scol + 8] = bv1;
        } else {
#if HAS_GLL
            gll16((void*)(Bh + (long)(n0 + drow) * ldb + k0 + dcol), (void*)(Bs + wv * 512));
            gll16((void*)(Bh + (long)(n0 + 64 + drow) * ldb + k0 + dcol), (void*)(Bs + 2048 + wv * 512));
#else
            *(uint4*)&Bs[srow * 32 + scol] = bv0;
            *(uint4*)&Bs[srow * 32 + scol + 8] = bv1;
#endif
        }
        __syncthreads();

        s16x8 af[4], bfg[4];
#pragma unroll
        for (int mi = 0; mi < 4; mi++) {
            int r = wm * 64 + mi * 16 + lrow;
            af[mi] = *(const s16x8*)&As[r * 32 + quad * 8];
        }
#pragma unroll
        for (int ni = 0; ni < 4; ni++) {
            int r = wn * 64 + ni * 16 + lrow;
            bfg[ni] = *(const s16x8*)&Bs[r * 32 + quad * 8];
        }
#pragma unroll
        for (int mi = 0; mi < 4; mi++)
#pragma unroll
            for (int ni = 0; ni < 4; ni++)
                acc[mi][ni] = __builtin_amdgcn_mfma_f32_16x16x32_bf16(af[mi], bfg[ni], acc[mi][ni], 0, 0, 0);
    }

    // epilogue: C/D layout col = lane&15, row = quad*4 + i (verified)
#pragma unroll
    for (int mi = 0; mi < 4; mi++) {
#pragma unroll
        for (int ni = 0; ni < 4; ni++) {
            int col = n0 + wn * 64 + ni * 16 + lrow;
            float bv = biasp ? biasp[col] : 0.0f;
#pragma unroll
            for (int i = 0; i < 4; i++) {
                int row = m0 + wm * 64 + mi * 16 + quad * 4 + i;
                float v = accSign * acc[mi][ni][i] + bv;
                if (auxType == 1) v += auxf[(long)row * ldaux + col];
                else if (auxType == 2) v += (float)auxh[(long)row * ldaux + col];
                if (relu) v = fmaxf(v, 0.0f);
                if (cF32) Cf[(long)row * ldc + col] = v;
                else Ch[(long)row * ldc + col] = (bf16)v;
            }
        }
    }
}

// ---------------- conversions ----------------
__global__ __launch_bounds__(256) void cvt4(const float* __restrict__ in, bf16* __restrict__ out, int n4) {
    int i = blockIdx.x * 256 + threadIdx.x;
    if (i < n4) {
        float4 f = ((const float4*)in)[i];
        ushort4 u; u.x = f2b(f.x); u.y = f2b(f.y); u.z = f2b(f.z); u.w = f2b(f.w);
        ((ushort4*)out)[i] = u;
    }
}

struct WCvt {
    const float* in[9];
    bf16* out[9];
    int n4[9];
};
__global__ __launch_bounds__(256) void cvt_weights(WCvt wc) {
    int t = blockIdx.y;
    int n4 = wc.n4[t];
    const float4* in = (const float4*)wc.in[t];
    ushort4* out = (ushort4*)wc.out[t];
    for (int i = blockIdx.x * 256 + threadIdx.x; i < n4; i += gridDim.x * 256) {
        float4 f = in[i];
        ushort4 u; u.x = f2b(f.x); u.y = f2b(f.y); u.z = f2b(f.z); u.w = f2b(f.w);
        out[i] = u;
    }
}

// ---------------- elementwise / normalization ----------------
__global__ __launch_bounds__(256) void l2norm_rows(bf16* __restrict__ Q) {
    bf16* q = Q + (long)blockIdx.x * KF;
    ushort4 u = ((ushort4*)q)[threadIdx.x];
    float v0 = b2f(u.x), v1 = b2f(u.y), v2 = b2f(u.z), v3 = b2f(u.w);
    float ss = blockReduceSum(v0 * v0 + v1 * v1 + v2 * v2 + v3 * v3);
    float inv = 1.0f / fmaxf(sqrtf(ss), 1e-12f);
    u.x = f2b(v0 * inv); u.y = f2b(v1 * inv); u.z = f2b(v2 * inv); u.w = f2b(v3 * inv);
    ((ushort4*)q)[threadIdx.x] = u;
}

__global__ __launch_bounds__(256) void softmax_rows(bf16* __restrict__ P) {
    bf16* p = P + (long)blockIdx.x * LL;
    ushort4 a = ((ushort4*)p)[2 * threadIdx.x];
    ushort4 b = ((ushort4*)p)[2 * threadIdx.x + 1];
    float v[8] = {b2f(a.x), b2f(a.y), b2f(a.z), b2f(a.w), b2f(b.x), b2f(b.y), b2f(b.z), b2f(b.w)};
    float mx = -1e30f;
#pragma unroll
    for (int i = 0; i < 8; i++) mx = fmaxf(mx, v[i]);
    mx = blockReduceMax(mx);
    float s = 0.0f;
#pragma unroll
    for (int i = 0; i < 8; i++) { v[i] = __expf(v[i] - mx); s += v[i]; }
    s = blockReduceSum(s);
    float inv = 1.0f / s;
    a.x = f2b(v[0]*inv); a.y = f2b(v[1]*inv); a.z = f2b(v[2]*inv); a.w = f2b(v[3]*inv);
    b.x = f2b(v[4]*inv); b.y = f2b(v[5]*inv); b.z = f2b(v[6]*inv); b.w = f2b(v[7]*inv);
    ((ushort4*)p)[2 * threadIdx.x] = a;
    ((ushort4*)p)[2 * threadIdx.x + 1] = b;
}

__global__ __launch_bounds__(256) void zero_cs(float* __restrict__ cs) {
    cs[blockIdx.x * 256 + threadIdx.x] = 0.0f;
}

// two-stage column sums: grid (LL/256, 16, nb); each block sums 128 rows, one atomic/thread
__global__ __launch_bounds__(256) void colsum2(const bf16* __restrict__ P, float* __restrict__ cs) {
    int col = blockIdx.x * 256 + threadIdx.x;
    int rc = blockIdx.y;
    int b = blockIdx.z;
    const bf16* p = P + (long)b * LL * LL + (long)rc * 128 * LL + col;
    float s = 0.0f;
#pragma unroll 4
    for (int r = 0; r < 128; r++) s += (float)p[(long)r * LL];
    atomicAdd(&cs[(long)b * LL + col], s);
}

// Vt[b][e][m] /= (1e-9 + Cs[b][m])   grid (DM, nb)
__global__ __launch_bounds__(256) void scale_vt(bf16* __restrict__ vt, const float* __restrict__ cs) {
    int e = blockIdx.x, b = blockIdx.y;
    bf16* row = vt + ((long)b * DM + e) * LL;
    const float* c = cs + (long)b * LL;
#pragma unroll
    for (int i = 0; i < 8; i++) {
        int m = threadIdx.x + i * 256;
        row[m] = (bf16)((float)row[m] / (1e-9f + c[m]));
    }
}

__global__ __launch_bounds__(256) void ln_rows(const bf16* __restrict__ in, void* __restrict__ out,
                                               int outF32,
                                               const float* __restrict__ g, const float* __restrict__ b,
                                               const float* __restrict__ aux) {
    long base = (long)blockIdx.x * 256;
    float v = (float)in[base + threadIdx.x];
    if (aux) v += aux[base + threadIdx.x];
    float mean = blockReduceSum(v) * (1.0f / 256.0f);
    float d = v - mean;
    float var = blockReduceSum(d * d) * (1.0f / 256.0f);
    float o = d * rsqrtf(var + 1e-5f) * g[threadIdx.x] + b[threadIdx.x];
    if (outF32) ((float*)out)[base + threadIdx.x] = o;
    else ((bf16*)out)[base + threadIdx.x] = (bf16)o;
}

__global__ __launch_bounds__(256) void ln_cat(bf16* __restrict__ cat, const float* __restrict__ g,
                                              const float* __restrict__ bb) {
    long n = blockIdx.x;
    int h = blockIdx.y;
    bf16* x = cat + n * HD + (long)h * DM;
    float v = (float)x[threadIdx.x];
    float mean = blockReduceSum(v) * (1.0f / 256.0f);
    float d = v - mean;
    float var = blockReduceSum(d * d) * (1.0f / 256.0f);
    x[threadIdx.x] = (bf16)(d * rsqrtf(var + 1e-5f) * g[h * DM + threadIdx.x] + bb[h * DM + threadIdx.x]);
}

// ---------------- host ----------------
extern "C" void kernel_launch(void* const* d_in, const int* in_sizes, int n_in,
                              void* d_out, int out_size, void* d_ws, size_t ws_size,
                              hipStream_t stream) {
    const float* src  = (const float*)d_in[0];
    const float* WK   = (const float*)d_in[1];
    const float* WQ   = (const float*)d_in[2];
    const float* WV   = (const float*)d_in[3];
    const float* TC   = (const float*)d_in[4];
    const float* ENw1 = (const float*)d_in[5];
    const float* ENb1 = (const float*)d_in[6];
    const float* ENw2 = (const float*)d_in[7];
    const float* ENb2 = (const float*)d_in[8];
    const float* ENg  = (const float*)d_in[9];
    const float* ENbt = (const float*)d_in[10];
    const float* Wout = (const float*)d_in[11];
    const float* L1w  = (const float*)d_in[12];
    const float* L1b  = (const float*)d_in[13];
    const float* L2w  = (const float*)d_in[14];
    const float* L2b  = (const float*)d_in[15];
    const float* N1g  = (const float*)d_in[16];
    const float* N1b  = (const float*)d_in[17];
    const float* N2g  = (const float*)d_in[18];
    const float* N2b  = (const float*)d_in[19];

    const size_t COMPACT_FLOOR = 34700000;
    const size_t FAST_FLOOR  = 92307456;               // fast path, f32 weights in GEMM
    const size_t FASTW_FLOOR = 92307456 + 11010048;    // + bf16 weight copies (103.3 MB)
    if (ws_size < COMPACT_FLOOR || out_size != NN * DM || n_in != 20) {
        float val;
        if (n_in != 20) val = 32768.0f + (float)n_in;
        else if (out_size != NN * DM) val = 49152.0f;
        else val = 16384.0f + 128.0f * (float)(unsigned)(ws_size >> 20);
        sentinel_kernel<<<1, 64, 0, stream>>>((float*)d_out, val);
        return;
    }

    char* w = (char*)d_ws;
    auto G = [&](const void* A, int aF, int lda, long sA,
                 const void* B, int bF, int ldb, long sB,
                 void* C, int cF, int ldc, long sC,
                 int M, int Nn, int Kc, int nb,
                 const float* bias, long sBias,
                 const void* aux, int auxT, int ldaux, long sAux,
                 float sgn, int relu) {
        gemm_nt<<<dim3(M / 128, Nn / 128, nb), dim3(256), 0, stream>>>(
            A, aF, lda, sA, B, bF, ldb, sB, C, cF, ldc, sC, Kc,
            bias, sBias, aux, auxT, ldaux, sAux, sgn, relu);
    };

    if (ws_size >= FAST_FLOOR) {
        // ======== FAST PATH ========
        bf16*  Sb  = (bf16*)(w + 0);           //  4 MB src bf16
        bf16*  Q   = (bf16*)(w + 4194304);     // 16 MB  (alias: Ru, Ffh)
        bf16*  K   = (bf16*)(w + 20971520);    // 16 MB  (alias: Hid)
        bf16*  Vt  = (bf16*)(w + 37748736);    //  4 MB  (alias: Attn, Yp)
        bf16*  P   = (bf16*)(w + 41943040);    // 32 MB  (alias: Cat)
        bf16*  Su  = (bf16*)(w + 75497472);    // 16 MB  (alias: Xln)
        float* Cs  = (float*)(w + 92274688);   // 32 KB
        bf16* Ru = Q; bf16* Hid = K; bf16* Cat = P;
        bf16* Attn = Vt; bf16* Xln = Su; bf16* Ffh = Q; bf16* Yp = Vt;

        // optional bf16 weight copies
        const int haveWb = (ws_size >= FASTW_FLOOR) ? 1 : 0;
        char* wb = w + 92307456;
        bf16* WKb   = (bf16*)(wb + 0);
        bf16* WQb   = (bf16*)(wb + 2097152);
        bf16* WVb   = (bf16*)(wb + 4194304);
        bf16* TCb   = (bf16*)(wb + 4718592);
        bf16* ENw1b = (bf16*)(wb + 5242880);
        bf16* ENw2b = (bf16*)(wb + 7340032);
        bf16* Woutb = (bf16*)(wb + 9437184);
        bf16* L1wb  = (bf16*)(wb + 9961472);
        bf16* L2wb  = (bf16*)(wb + 10485760);
        if (haveWb) {
            WCvt wc;
            wc.in[0] = WK;   wc.out[0] = WKb;   wc.n4[0] = 262144;
            wc.in[1] = WQ;   wc.out[1] = WQb;   wc.n4[1] = 262144;
            wc.in[2] = WV;   wc.out[2] = WVb;   wc.n4[2] = 65536;
            wc.in[3] = TC;   wc.out[3] = TCb;   wc.n4[3] = 65536;
            wc.in[4] = ENw1; wc.out[4] = ENw1b; wc.n4[4] = 262144;
            wc.in[5] = ENw2; wc.out[5] = ENw2b; wc.n4[5] = 262144;
            wc.in[6] = Wout; wc.out[6] = Woutb; wc.n4[6] = 65536;
            wc.in[7] = L1w;  wc.out[7] = L1wb;  wc.n4[7] = 65536;
            wc.in[8] = L2w;  wc.out[8] = L2wb;  wc.n4[8] = 65536;
            cvt_weights<<<dim3(256, 9), 256, 0, stream>>>(wc);
        }
        const int wF = haveWb ? 0 : 1;   // weight dtype flag for GEMM
        auto WP = [&](const void* f32p, const void* b16p, long off) {
            return haveWb ? (const void*)((const bf16*)b16p + off)
                          : (const void*)((const float*)f32p + off);
        };

        cvt4<<<2048, 256, 0, stream>>>(src, Sb, NN * DM / 4);

        for (int h = 0; h < HN; h++) {
            G(Sb, 0, DM, 0, WP(WQ, WQb, (long)h * KF * DM), wF, DM, 0, Q, 0, KF, 0,
              NN, KF, DM, 1, nullptr, 0, nullptr, 0, 0, 0, 1.0f, 0);
            G(Sb, 0, DM, 0, WP(WK, WKb, (long)h * KF * DM), wF, DM, 0, K, 0, KF, 0,
              NN, KF, DM, 1, nullptr, 0, nullptr, 0, 0, 0, 1.0f, 0);
            G(WP(WV, WVb, (long)h * DM * DM), wF, DM, 0, Sb, 0, BB * DM, DM,
              Vt, 0, LL, (long)DM * LL,
              DM, LL, DM, BB, nullptr, 0, nullptr, 0, 0, 0, 1.0f, 0);
            l2norm_rows<<<NN, 256, 0, stream>>>(Q);
            l2norm_rows<<<NN, 256, 0, stream>>>(K);
            G(Q, 0, BB * KF, KF, K, 0, BB * KF, KF, P, 0, LL, (long)LL * LL,
              LL, LL, KF, BB, nullptr, 0, nullptr, 0, 0, 0, 1.0f, 0);
            softmax_rows<<<BB * LL, 256, 0, stream>>>(P);
            zero_cs<<<BB * LL / 256, 256, 0, stream>>>(Cs);
            colsum2<<<dim3(LL / 256, 16, BB), 256, 0, stream>>>(P, Cs);
            scale_vt<<<dim3(DM, BB), 256, 0, stream>>>(Vt, Cs);
            G(P, 0, LL, (long)LL * LL, Vt, 0, LL, (long)DM * LL,
              Su + (long)h * NN * DM, 0, BB * DM, DM,
              LL, DM, LL, BB, nullptr, 0, Sb, 2, BB * DM, DM, -1.0f, 0);
        }
        G(Su, 0, DM, (long)NN * DM, WP(TC, TCb, 0), wF, DM, (long)DM * DM,
          Ru, 0, DM, (long)NN * DM,
          NN, DM, DM, HN, nullptr, 0, nullptr, 0, 0, 0, 1.0f, 1);
        for (int h = 0; h < HN; h++) {
            G(Ru + (long)h * NN * DM, 0, DM, 0, WP(ENw1, ENw1b, (long)h * FFD * DM), wF, DM, 0,
              Hid, 0, FFD, 0, NN, FFD, DM, 1, ENb1 + (long)h * FFD, 0, nullptr, 0, 0, 0, 1.0f, 1);
            G(Hid, 0, FFD, 0, WP(ENw2, ENw2b, (long)h * DM * FFD), wF, FFD, 0,
              Cat + (long)h * DM, 0, HD, 0, NN, DM, FFD, 1,
              ENb2 + (long)h * DM, 0, Ru + (long)h * NN * DM, 2, DM, 0, 1.0f, 0);
        }
        ln_cat<<<dim3(NN, HN), 256, 0, stream>>>(Cat, ENg, ENbt);
        G(Cat, 0, HD, 0, WP(Wout, Woutb, 0), wF, HD, 0, Attn, 0, DM, 0,
          NN, DM, HD, 1, nullptr, 0, nullptr, 0, 0, 0, 1.0f, 0);
        ln_rows<<<NN, 256, 0, stream>>>(Attn, Xln, 0, N1g, N1b, src);
        G(Xln, 0, DM, 0, WP(L1w, L1wb, 0), wF, DM, 0, Ffh, 0, FFD, 0,
          NN, FFD, DM, 1, L1b, 0, nullptr, 0, 0, 0, 1.0f, 1);
        G(Ffh, 0, FFD, 0, WP(L2w, L2wb, 0), wF, FFD, 0, Yp, 0, DM, 0,
          NN, DM, FFD, 1, L2b, 0, Xln, 2, DM, 0, 1.0f, 0);
        ln_rows<<<NN, 256, 0, stream>>>(Yp, (float*)d_out, 1, N2g, N2b, nullptr);
    } else {
        // ======== COMPACT PATH (round-8 verified sequence) ========
        bf16*  S0 = (bf16*)(w + 0);
        bf16*  S1 = (bf16*)(w + 16777216);
        bf16*  S2 = (bf16*)(w + 20971520);
        bf16*  S3 = (bf16*)(w + 25165824);
        bf16*  S4 = (bf16*)(w + 26214400);
        bf16*  S5 = (bf16*)(w + 30408704);
        float* Cs = (float*)(w + 34603008);

        for (int h = 0; h < HN; h++) {
            for (int b = 0; b < BB; b++) {
                G(src + b * DM, 1, BB * DM, 0, WQ + (long)h * KF * DM, 1, DM, 0,
                  S1, 0, KF, 0, LL, KF, DM, 1, nullptr, 0, nullptr, 0, 0, 0, 1.0f, 0);
                G(src + b * DM, 1, BB * DM, 0, WK + (long)h * KF * DM, 1, DM, 0,
                  S2, 0, KF, 0, LL, KF, DM, 1, nullptr, 0, nullptr, 0, 0, 0, 1.0f, 0);
                G(WV + (long)h * DM * DM, 1, DM, 0, src + b * DM, 1, BB * DM, 0,
                  S3, 0, LL, 0, DM, LL, DM, 1, nullptr, 0, nullptr, 0, 0, 0, 1.0f, 0);
                l2norm_rows<<<LL, 256, 0, stream>>>(S1);
                l2norm_rows<<<LL, 256, 0, stream>>>(S2);
                G(S1, 0, KF, 0, S2, 0, KF, 0, S0, 0, LL, 0,
                  LL, LL, KF, 1, nullptr, 0, nullptr, 0, 0, 0, 1.0f, 0);
                softmax_rows<<<LL, 256, 0, stream>>>(S0);
                zero_cs<<<LL / 256, 256, 0, stream>>>(Cs);
                colsum2<<<dim3(LL / 256, 16, 1), 256, 0, stream>>>(S0, Cs);
                scale_vt<<<dim3(DM, 1), 256, 0, stream>>>(S3, Cs);
                G(S0, 0, LL, 0, S3, 0, LL, 0, S4 + b * DM, 0, BB * DM, 0,
                  LL, DM, LL, 1, nullptr, 0, src + b * DM, 1, BB * DM, 0, -1.0f, 0);
            }
            G(S4, 0, DM, 0, TC + (long)h * DM * DM, 1, DM, 0, S1, 0, DM, 0,
              NN, DM, DM, 1, nullptr, 0, nullptr, 0, 0, 0, 1.0f, 1);
            G(S1, 0, DM, 0, ENw1 + (long)h * FFD * DM, 1, DM, 0, S0, 0, FFD, 0,
              NN, FFD, DM, 1, ENb1 + (long)h * FFD, 0, nullptr, 0, 0, 0, 1.0f, 1);
            G(S0, 0, FFD, 0, ENw2 + (long)h * DM * FFD, 1, FFD, 0, S2, 0, DM, 0,
              NN, DM, FFD, 1, ENb2 + (long)h * DM, 0, S1, 2, DM, 0, 1.0f, 0);
            ln_rows<<<NN, 256, 0, stream>>>(S2, S2, 0, ENg + (long)h * DM, ENbt + (long)h * DM, nullptr);
            G(S2, 0, DM, 0, Wout + (long)h * DM, 1, HD, 0, S5, 0, DM, 0,
              NN, DM, DM, 1, nullptr, 0, (h == 0) ? nullptr : (const void*)S5,
              (h == 0) ? 0 : 2, DM, 0, 1.0f, 0);
        }
        ln_rows<<<NN, 256, 0, stream>>>(S5, S1, 0, N1g, N1b, src);
        G(S1, 0, DM, 0, L1w, 1, DM, 0, S0, 0, FFD, 0,
          NN, FFD, DM, 1, L1b, 0, nullptr, 0, 0, 0, 1.0f, 1);
        G(S0, 0, FFD, 0, L2w, 1, FFD, 0, S2, 0, DM, 0,
          NN, DM, FFD, 1, L2b, 0, S1, 2, DM, 0, 1.0f, 0);
        ln_rows<<<NN, 256, 0, stream>>>(S2, (float*)d_out, 1, N2g, N2b, nullptr);
    }
}